// Round 1
// baseline (1669.059 us; speedup 1.0000x reference)
//
#include <hip/hip_runtime.h>
#include <math.h>

#define T_STEPS 2048
#define B_SZ 16
#define D_SZ 1024
#define N_SZ 64
#define M_ROWS (T_STEPS * B_SZ)   // 32768
#define NOUT (4 * N_SZ)           // 256

__device__ __forceinline__ float wave_reduce_sum(float v) {
#pragma unroll
  for (int off = 1; off < 64; off <<= 1)
    v += __shfl_xor(v, off, 64);
  return v;
}

// ---------------------------------------------------------------------------
// Kernel 1: proj[m, n] = dot(x[m, :], W[n, :])   (M=32768, K=1024, N=256)
// 64x64 block tile, 256 threads, each thread computes 4x4 outputs.
// LDS tiles stored transposed [k][row] with pad 68 (16B-aligned, conflict-ok).
// ---------------------------------------------------------------------------
__global__ __launch_bounds__(256) void gemm_proj(const float* __restrict__ x,
                                                 const float* __restrict__ W,
                                                 float* __restrict__ proj) {
  __shared__ float xs[32][68];
  __shared__ float ws[32][68];
  const int tid = threadIdx.x;
  const int n0 = blockIdx.x * 64;   // n fast dim -> blocks sharing x-tile adjacent
  const int m0 = blockIdx.y * 64;
  const int mi = tid >> 4;          // 0..15
  const int ni = tid & 15;          // 0..15

  float acc[4][4];
#pragma unroll
  for (int r = 0; r < 4; ++r)
#pragma unroll
    for (int c = 0; c < 4; ++c) acc[r][c] = 0.f;

  for (int k0 = 0; k0 < D_SZ; k0 += 32) {
#pragma unroll
    for (int rep = 0; rep < 2; ++rep) {
      const int f = tid + rep * 256;      // 0..511 float4 slots
      const int row = f >> 3;             // 0..63
      const int c4 = (f & 7) * 4;         // 0,4,..,28
      const float4 xv = *reinterpret_cast<const float4*>(
          &x[(size_t)(m0 + row) * D_SZ + k0 + c4]);
      xs[c4 + 0][row] = xv.x; xs[c4 + 1][row] = xv.y;
      xs[c4 + 2][row] = xv.z; xs[c4 + 3][row] = xv.w;
      const float4 wv = *reinterpret_cast<const float4*>(
          &W[(size_t)(n0 + row) * D_SZ + k0 + c4]);
      ws[c4 + 0][row] = wv.x; ws[c4 + 1][row] = wv.y;
      ws[c4 + 2][row] = wv.z; ws[c4 + 3][row] = wv.w;
    }
    __syncthreads();
#pragma unroll
    for (int k = 0; k < 32; ++k) {
      float av[4], bv[4];
      *reinterpret_cast<float4*>(av) =
          *reinterpret_cast<const float4*>(&xs[k][mi * 4]);
      *reinterpret_cast<float4*>(bv) =
          *reinterpret_cast<const float4*>(&ws[k][ni * 4]);
#pragma unroll
      for (int r = 0; r < 4; ++r)
#pragma unroll
        for (int c = 0; c < 4; ++c)
          acc[r][c] = fmaf(av[r], bv[c], acc[r][c]);
    }
    __syncthreads();
  }

#pragma unroll
  for (int r = 0; r < 4; ++r) {
    const size_t row = (size_t)(m0 + mi * 4 + r);
    float4 o;
    o.x = acc[r][0]; o.y = acc[r][1]; o.z = acc[r][2]; o.w = acc[r][3];
    *reinterpret_cast<float4*>(&proj[row * NOUT + n0 + ni * 4]) = o;
  }
}

// ---------------------------------------------------------------------------
// Kernel 2: in-place per (t,b): k-slot -> k/(||k||+eps); g-slot -> sigmoid(g+b)
// One wave per m = t*B+b.
// ---------------------------------------------------------------------------
__global__ __launch_bounds__(256) void norm_gate(float* __restrict__ proj,
                                                 const float* __restrict__ b_gate) {
  const int wid = threadIdx.x >> 6;
  const int lane = threadIdx.x & 63;
  const int m = blockIdx.x * 4 + wid;           // 0..32767
  float* p = proj + (size_t)m * NOUT;
  const float k = p[lane];
  const float ss = wave_reduce_sum(k * k);
  p[lane] = k / (sqrtf(ss) + 1e-6f);
  const float g = p[192 + lane];
  p[192 + lane] = 1.f / (1.f + expf(-(g + b_gate[lane])));
}

// ---------------------------------------------------------------------------
// Kernel 3: sequential scan. One wave per (b, i): lane j holds S[b,i,j].
// ---------------------------------------------------------------------------
__global__ __launch_bounds__(256) void scan_kernel(const float* __restrict__ proj,
                                                   const float* __restrict__ S0,
                                                   float* __restrict__ out,
                                                   float* __restrict__ Sfin) {
  const int wid = threadIdx.x >> 6;
  const int lane = threadIdx.x & 63;
  const int gw = blockIdx.x * 4 + wid;          // 0..1023
  const int b = gw >> 6;
  const int i = gw & 63;

  float S = S0[(size_t)b * (N_SZ * N_SZ) + i * N_SZ + lane];

  for (int t = 0; t < T_STEPS; ++t) {
    const float* p = proj + ((size_t)t * B_SZ + b) * NOUT;
    const float kn  = p[lane];         // normalized k
    const float qv  = p[128 + lane];   // q
    const float vv  = p[64 + i];       // v scalar for this row
    const float dec = p[192 + i];      // precomputed decay scalar

    const float r = wave_reduce_sum(S * kn);
    const float delta = vv - r;
    S = fmaf(dec, S, delta * kn);
    const float sq = wave_reduce_sum(S * qv);
    if (lane == 0) {
      // out = Sq * silu(Sq) = Sq^2 * sigmoid(Sq)
      out[(size_t)t * (B_SZ * N_SZ) + b * N_SZ + i] =
          sq * sq / (1.f + expf(-sq));
    }
  }
  Sfin[(size_t)b * (N_SZ * N_SZ) + i * N_SZ + lane] = S;
}

// ---------------------------------------------------------------------------
extern "C" void kernel_launch(void* const* d_in, const int* in_sizes, int n_in,
                              void* d_out, int out_size, void* d_ws, size_t ws_size,
                              hipStream_t stream) {
  const float* x      = (const float*)d_in[0];
  const float* S0     = (const float*)d_in[1];
  const float* W      = (const float*)d_in[2];
  const float* b_gate = (const float*)d_in[3];
  float* out  = (float*)d_out;
  float* proj = (float*)d_ws;                   // 32768 * 256 * 4B = 33.5 MB

  hipLaunchKernelGGL(gemm_proj, dim3(NOUT / 64, M_ROWS / 64), dim3(256), 0, stream,
                     x, W, proj);
  hipLaunchKernelGGL(norm_gate, dim3(M_ROWS / 4), dim3(256), 0, stream,
                     proj, b_gate);
  hipLaunchKernelGGL(scan_kernel, dim3(1024 / 4), dim3(256), 0, stream,
                     proj, S0, out, out + (size_t)T_STEPS * B_SZ * N_SZ);
}

// Round 2
// 722.970 us; speedup vs baseline: 2.3086x; 2.3086x over previous
//
#include <hip/hip_runtime.h>
#include <math.h>

#define T_STEPS 2048
#define B_SZ 16
#define D_SZ 1024
#define N_SZ 64
#define M_ROWS (T_STEPS * B_SZ)   // 32768
#define NOUT (4 * N_SZ)           // 256

// ---------------------------------------------------------------------------
// DPP-based full-wave (64-lane) sum, result uniform across all lanes.
// Butterfly xor1/xor2 via quad_perm, xor4 via row_half_mirror, xor8 via
// row_mirror (valid because prior levels make quads uniform), then a
// readlane tree across the four 16-lane rows.
// ---------------------------------------------------------------------------
#define DPP_ADD(x, ctrl)                                                      \
  ((x) + __int_as_float(__builtin_amdgcn_update_dpp(                          \
             0, __float_as_int(x), (ctrl), 0xF, 0xF, true)))

__device__ __forceinline__ float wave_sum64(float v) {
  v = DPP_ADD(v, 0xB1);   // quad_perm [1,0,3,2]  : xor 1
  v = DPP_ADD(v, 0x4E);   // quad_perm [2,3,0,1]  : xor 2
  v = DPP_ADD(v, 0x141);  // row_half_mirror      : xor 4 (quads uniform)
  v = DPP_ADD(v, 0x140);  // row_mirror           : xor 8 (8-groups uniform)
  const int vi = __float_as_int(v);
  const float a = __int_as_float(__builtin_amdgcn_readlane(vi, 0));
  const float b = __int_as_float(__builtin_amdgcn_readlane(vi, 16));
  const float c = __int_as_float(__builtin_amdgcn_readlane(vi, 32));
  const float d = __int_as_float(__builtin_amdgcn_readlane(vi, 48));
  return (a + b) + (c + d);
}

// ---------------------------------------------------------------------------
// Kernel 1: proj[m, n] = dot(x[m, :], W[n, :])   (M=32768, K=1024, N=256)
// 64x64 block tile, 256 threads, each thread computes 4x4 outputs.
// ---------------------------------------------------------------------------
__global__ __launch_bounds__(256) void gemm_proj(const float* __restrict__ x,
                                                 const float* __restrict__ W,
                                                 float* __restrict__ proj) {
  __shared__ float xs[32][68];
  __shared__ float ws[32][68];
  const int tid = threadIdx.x;
  const int n0 = blockIdx.x * 64;
  const int m0 = blockIdx.y * 64;
  const int mi = tid >> 4;
  const int ni = tid & 15;

  float acc[4][4];
#pragma unroll
  for (int r = 0; r < 4; ++r)
#pragma unroll
    for (int c = 0; c < 4; ++c) acc[r][c] = 0.f;

  for (int k0 = 0; k0 < D_SZ; k0 += 32) {
#pragma unroll
    for (int rep = 0; rep < 2; ++rep) {
      const int f = tid + rep * 256;
      const int row = f >> 3;
      const int c4 = (f & 7) * 4;
      const float4 xv = *reinterpret_cast<const float4*>(
          &x[(size_t)(m0 + row) * D_SZ + k0 + c4]);
      xs[c4 + 0][row] = xv.x; xs[c4 + 1][row] = xv.y;
      xs[c4 + 2][row] = xv.z; xs[c4 + 3][row] = xv.w;
      const float4 wv = *reinterpret_cast<const float4*>(
          &W[(size_t)(n0 + row) * D_SZ + k0 + c4]);
      ws[c4 + 0][row] = wv.x; ws[c4 + 1][row] = wv.y;
      ws[c4 + 2][row] = wv.z; ws[c4 + 3][row] = wv.w;
    }
    __syncthreads();
#pragma unroll
    for (int k = 0; k < 32; ++k) {
      float av[4], bv[4];
      *reinterpret_cast<float4*>(av) =
          *reinterpret_cast<const float4*>(&xs[k][mi * 4]);
      *reinterpret_cast<float4*>(bv) =
          *reinterpret_cast<const float4*>(&ws[k][ni * 4]);
#pragma unroll
      for (int r = 0; r < 4; ++r)
#pragma unroll
        for (int c = 0; c < 4; ++c)
          acc[r][c] = fmaf(av[r], bv[c], acc[r][c]);
    }
    __syncthreads();
  }

#pragma unroll
  for (int r = 0; r < 4; ++r) {
    const size_t row = (size_t)(m0 + mi * 4 + r);
    float4 o;
    o.x = acc[r][0]; o.y = acc[r][1]; o.z = acc[r][2]; o.w = acc[r][3];
    *reinterpret_cast<float4*>(&proj[row * NOUT + n0 + ni * 4]) = o;
  }
}

// ---------------------------------------------------------------------------
// Kernel 2: per (t,b) row of proj, IN-PLACE repack to scan-friendly layout:
//   new row = [ (kn[j], q[j]) x64 interleaved | (v[j], decay[j]) x64 ]
// where kn = k/(||k||+eps), decay = sigmoid(g + b_gate).
// One wave per row; explicit vmcnt(0) between the reads and the
// overlapping in-place writes.
// ---------------------------------------------------------------------------
__global__ __launch_bounds__(256) void norm_gate(float* __restrict__ proj,
                                                 const float* __restrict__ b_gate) {
  const int wid = threadIdx.x >> 6;
  const int lane = threadIdx.x & 63;
  const int m = blockIdx.x * 4 + wid;
  float* p = proj + (size_t)m * NOUT;
  const float kf = p[lane];
  const float vf = p[64 + lane];
  const float qf = p[128 + lane];
  const float gf = p[192 + lane];
  const float bg = b_gate[lane];
  const float ss = wave_sum64(kf * kf);
  const float kn = kf / (sqrtf(ss) + 1e-6f);
  const float dec = 1.f / (1.f + expf(-(gf + bg)));
  asm volatile("s_waitcnt vmcnt(0)" ::: "memory");
  float2* pp = reinterpret_cast<float2*>(p);
  float2 a; a.x = kn; a.y = qf;
  float2 c; c.x = vf; c.y = dec;
  pp[lane] = a;        // (kn, q)
  pp[64 + lane] = c;   // (v, dec)
}

// ---------------------------------------------------------------------------
// Kernel 3: sequential scan. One wave per (b, i): lane j holds S[b,i,j].
// Per step, three INDEPENDENT parallel reductions:
//   r1 = S.kn, r2 = S.q, r3 = kn.q
//   delta = v - r1; S = dec*S + delta*kn; Sq_new = dec*r2 + delta*r3.
// Inter-step critical path = one DPP reduce + 2 fma.
// Proj rows prefetched 4 steps ahead (register double-buffer).
// ---------------------------------------------------------------------------
__global__ __launch_bounds__(256) void scan_kernel(const float* __restrict__ proj,
                                                   const float* __restrict__ S0,
                                                   float* __restrict__ out,
                                                   float* __restrict__ Sfin) {
  const int wid = threadIdx.x >> 6;
  const int lane = threadIdx.x & 63;
  const int gw = blockIdx.x * 4 + wid;          // 0..1023
  const int b = gw >> 6;
  const int i = gw & 63;

  float S = S0[(size_t)b * (N_SZ * N_SZ) + i * N_SZ + lane];
  const float2* base = reinterpret_cast<const float2*>(proj);  // row = 128 float2

  float2 knqA[4], vdA[4], knqB[4], vdB[4];

#pragma unroll
  for (int u = 0; u < 4; ++u) {
    const float2* p = base + (size_t)(u * B_SZ + b) * 128;
    knqA[u] = p[lane];
    vdA[u] = p[64 + i];
  }

  for (int t0 = 0; t0 < T_STEPS; t0 += 4) {
    const int tn = (t0 + 4 < T_STEPS) ? (t0 + 4) : (T_STEPS - 4);
#pragma unroll
    for (int u = 0; u < 4; ++u) {
      const float2* p = base + (size_t)((tn + u) * B_SZ + b) * 128;
      knqB[u] = p[lane];
      vdB[u] = p[64 + i];
    }
#pragma unroll
    for (int u = 0; u < 4; ++u) {
      const float kn = knqA[u].x;
      const float qv = knqA[u].y;
      const float r1 = wave_sum64(S * kn);
      const float r2 = wave_sum64(S * qv);
      const float r3 = wave_sum64(kn * qv);
      const float delta = vdA[u].x - r1;
      const float dec = vdA[u].y;
      S = fmaf(dec, S, delta * kn);
      const float sq = fmaf(dec, r2, delta * r3);
      if (lane == 0) {
        const float sig = __fdividef(1.f, 1.f + __expf(-sq));
        out[(size_t)(t0 + u) * (B_SZ * N_SZ) + b * N_SZ + i] = sq * sq * sig;
      }
    }
#pragma unroll
    for (int u = 0; u < 4; ++u) { knqA[u] = knqB[u]; vdA[u] = vdB[u]; }
  }
  Sfin[(size_t)b * (N_SZ * N_SZ) + i * N_SZ + lane] = S;
}

// ---------------------------------------------------------------------------
extern "C" void kernel_launch(void* const* d_in, const int* in_sizes, int n_in,
                              void* d_out, int out_size, void* d_ws, size_t ws_size,
                              hipStream_t stream) {
  const float* x      = (const float*)d_in[0];
  const float* S0     = (const float*)d_in[1];
  const float* W      = (const float*)d_in[2];
  const float* b_gate = (const float*)d_in[3];
  float* out  = (float*)d_out;
  float* proj = (float*)d_ws;                   // 32768 * 256 * 4B = 33.5 MB

  hipLaunchKernelGGL(gemm_proj, dim3(NOUT / 64, M_ROWS / 64), dim3(256), 0, stream,
                     x, W, proj);
  hipLaunchKernelGGL(norm_gate, dim3(M_ROWS / 4), dim3(256), 0, stream,
                     proj, b_gate);
  hipLaunchKernelGGL(scan_kernel, dim3(1024 / 4), dim3(256), 0, stream,
                     proj, S0, out, out + (size_t)T_STEPS * B_SZ * N_SZ);
}